// Round 20
// baseline (342.343 us; speedup 1.0000x reference)
//
#include <hip/hip_runtime.h>
#include <hip/hip_bf16.h>

typedef _Float16 f16_t;
typedef unsigned int uint;
typedef __attribute__((ext_vector_type(8))) _Float16 f16x8;
typedef __attribute__((ext_vector_type(4))) _Float16 f16x4;
typedef __attribute__((ext_vector_type(4))) float f32x4;
typedef __attribute__((ext_vector_type(16))) float f32x16;

#define ROPE_C (13.287712379549449f / 64.0f)   // log2(10000)/64; invf(j)=exp2(-j*ROPE_C)

// ---------------- merged repack: x (blocks 0..2047), wq|wk|wv 96-pan (2048..10239), wo (10240..14335) ----------------
__global__ __launch_bounds__(256) void repack_all(const float* __restrict__ x,
                                                  const float* __restrict__ wq,
                                                  const float* __restrict__ wk,
                                                  const float* __restrict__ wv,
                                                  const float* __restrict__ wo,
                                                  uint16_t* __restrict__ xh,
                                                  uint16_t* __restrict__ wqkv,
                                                  uint16_t* __restrict__ woh)
{
    const int bid = blockIdx.x;
    const int tid = threadIdx.x;
    const int k4 = tid & 7;
    const int slot = k4 >> 1;
    const int so   = (k4 & 1) * 4;

    if (bid < 2048) {
        const int p  = bid >> 7;
        const int kb = bid & 127;
        const int rr = tid >> 3;
        uint16_t* bh = xh + ((size_t)p * 128 + kb) * 4096;
        #pragma unroll
        for (int it = 0; it < 4; ++it) {
            const int r = it * 32 + rr;
            const float4 v = *reinterpret_cast<const float4*>(
                &x[((size_t)p * 128 + r) * 4096 + kb * 32 + k4 * 4]);
            float f[4] = {v.x, v.y, v.z, v.w};
            f16x4 h;
            #pragma unroll
            for (int e = 0; e < 4; ++e) h[e] = (f16_t)f[e];
            const int pos = r * 32 + ((slot ^ ((r >> 1) & 3)) << 3) + so;
            *reinterpret_cast<f16x4*>(&bh[pos]) = h;
        }
    } else if (bid < 10240) {
        const int idx = bid - 2048;
        const int pan = idx >> 7;
        const int kb  = idx & 127;
        uint16_t* bh = wqkv + ((size_t)pan * 128 + kb) * 3072;
        #pragma unroll
        for (int it = 0; it < 3; ++it) {
            const int r = it * 32 + (tid >> 3);
            const int n = pan * 96 + r;
            const float* srow = (n < 4096) ? (wq + (size_t)n * 4096)
                              : (n < 5120) ? (wk + (size_t)(n - 4096) * 4096)
                                           : (wv + (size_t)(n - 5120) * 4096);
            const float4 v = *reinterpret_cast<const float4*>(srow + kb * 32 + k4 * 4);
            float f[4] = {v.x, v.y, v.z, v.w};
            f16x4 h;
            #pragma unroll
            for (int e = 0; e < 4; ++e) h[e] = (f16_t)f[e];
            const int pos = r * 32 + ((slot ^ ((r >> 1) & 3)) << 3) + so;
            *reinterpret_cast<f16x4*>(&bh[pos]) = h;
        }
    } else {
        const int idx = bid - 10240;
        const int p  = idx >> 7;
        const int kb = idx & 127;
        const int rr = tid >> 3;
        uint16_t* bh = woh + ((size_t)p * 128 + kb) * 4096;
        #pragma unroll
        for (int it = 0; it < 4; ++it) {
            const int r = it * 32 + rr;
            const float4 v = *reinterpret_cast<const float4*>(
                &wo[((size_t)p * 128 + r) * 4096 + kb * 32 + k4 * 4]);
            float f[4] = {v.x, v.y, v.z, v.w};
            f16x4 h;
            #pragma unroll
            for (int e = 0; e < 4; ++e) h[e] = (f16_t)f[e];
            const int pos = r * 32 + ((slot ^ ((r >> 1) & 3)) << 3) + so;
            *reinterpret_cast<f16x4*>(&bh[pos]) = h;
        }
    }
}

// ---------------- QKV GEMM: 128x192, fp16, BK=64, 2-buf, grid 512; 2-D XCD partition ----------------
__global__ __launch_bounds__(512) void gemm_qkv9(const uint16_t* __restrict__ xh,
                                                 const uint16_t* __restrict__ wqkv,
                                                 uint16_t* __restrict__ xq16,
                                                 uint16_t* __restrict__ xk16,
                                                 uint16_t* __restrict__ xv16)
{
    __shared__ char lds[2][40960];

    const int bid = blockIdx.x;
    const int xcd = bid & 7;
    const int i_  = bid >> 3;
    const int by = (xcd & 1) * 8 + (i_ & 7);
    const int bx = (xcd >> 1) * 8 + (i_ >> 3);
    const int tid = threadIdx.x;
    const int w = tid >> 6, lane = tid & 63;
    const int wm = w >> 2, wn = w & 3;
    const int fr = lane & 15, s4 = lane >> 4;

    const uint16_t* sp[5];
    int dof[5];
    int stridec[5];
    #pragma unroll
    for (int i = 0; i < 5; ++i) {
        const int c = w + 8 * i;
        if (c < 16) {
            const int kk = c >> 3, inner = c & 7;
            sp[i] = xh + (size_t)by * 524288 + kk * 4096 + inner * 512 + lane * 8;
            dof[i] = c * 1024;
            stridec[i] = 8192;
        } else {
            const int cb = c - 16;
            const int pan = cb / 12, rem = cb % 12;
            const int kk = rem / 6, inner = rem % 6;
            sp[i] = wqkv + (size_t)(bx * 2 + pan) * 393216 + kk * 3072 + inner * 512 + lane * 8;
            dof[i] = 16384 + cb * 1024;
            stridec[i] = 6144;
        }
    }

    f32x4 acc[4][3] = {};

    #pragma unroll
    for (int i = 0; i < 5; ++i)
        __builtin_amdgcn_global_load_lds(
            (const __attribute__((address_space(1))) void*)(sp[i]),
            (__attribute__((address_space(3))) void*)(&lds[0][0] + dof[i]), 16, 0, 0);
    asm volatile("s_waitcnt vmcnt(0)" ::: "memory");
    __builtin_amdgcn_s_barrier();
    __builtin_amdgcn_sched_barrier(0);

    for (int t = 0; t < 64; ++t) {
        const char* b = &lds[t & 1][0];
        if (t + 1 < 64) {
            char* nb = &lds[(t + 1) & 1][0];
            #pragma unroll
            for (int i = 0; i < 5; ++i)
                __builtin_amdgcn_global_load_lds(
                    (const __attribute__((address_space(1))) void*)(sp[i] + (size_t)(t + 1) * stridec[i]),
                    (__attribute__((address_space(3))) void*)(nb + dof[i]), 16, 0, 0);
        }
        #pragma unroll
        for (int kk = 0; kk < 2; ++kk) {
            f16x8 fb[3];
            #pragma unroll
            for (int j = 0; j < 3; ++j) {
                const int cbp = wn * 48 + j * 16 + fr;
                const int pan = (cbp >= 96) ? 1 : 0;
                const int rb = cbp - pan * 96;
                fb[j] = *reinterpret_cast<const f16x8*>(
                    b + 16384 + pan * 12288 + kk * 6144 + rb * 64 + ((s4 ^ ((rb >> 1) & 3)) << 4));
            }
            #pragma unroll
            for (int ri = 0; ri < 4; ++ri) {
                const int rloc = wm * 64 + ri * 16 + fr;
                f16x8 fh = *reinterpret_cast<const f16x8*>(
                    b + kk * 8192 + rloc * 64 + ((s4 ^ ((rloc >> 1) & 3)) << 4));
                __builtin_amdgcn_s_setprio(1);
                #pragma unroll
                for (int j = 0; j < 3; ++j)
                    acc[ri][j] = __builtin_amdgcn_mfma_f32_16x16x32_f16(fh, fb[j], acc[ri][j], 0, 0, 0);
                __builtin_amdgcn_s_setprio(0);
            }
        }
        asm volatile("s_waitcnt vmcnt(0)" ::: "memory");
        __builtin_amdgcn_s_barrier();
        __builtin_amdgcn_sched_barrier(0);
    }

    const int r0 = by * 128 + wm * 64 + s4 * 4;
    const int c0 = bx * 192 + wn * 48 + fr;
    #pragma unroll
    for (int ri = 0; ri < 4; ++ri)
        #pragma unroll
        for (int j = 0; j < 3; ++j) {
            const int col = c0 + j * 16;
            #pragma unroll
            for (int rr = 0; rr < 4; ++rr) {
                const int row = r0 + ri * 16 + rr;
                const f16_t v = (f16_t)acc[ri][j][rr];
                uint16_t bits;
                __builtin_memcpy(&bits, &v, 2);
                if (col < 4096)      xq16[(size_t)row * 4096 + col] = bits;
                else if (col < 5120) xk16[(size_t)row * 1024 + (col - 4096)] = bits;
                else                 xv16[(size_t)row * 1024 + (col - 5120)] = bits;
            }
        }
}

// ---------------- Output GEMM: 256x128, fp16, BK=64, 2-buf, grid 256; 2-D XCD partition ----------------
__global__ __launch_bounds__(512) void gemm_out8(const uint16_t* __restrict__ aoh,
                                                 const uint16_t* __restrict__ woh,
                                                 float* __restrict__ out)
{
    __shared__ char lds[2][49152];

    const int bid = blockIdx.x;
    const int xcd = bid & 7;
    const int i_  = bid >> 3;
    const int by = (xcd & 1) * 4 + (i_ & 3);
    const int bx = (xcd >> 1) * 8 + (i_ >> 2);
    const int tid = threadIdx.x;
    const int w = tid >> 6, lane = tid & 63;
    const int wm = w >> 2, wn = w & 3;
    const int fr = lane & 15, s4 = lane >> 4;

    const uint16_t* sp[6];
    int dof[6];
    #pragma unroll
    for (int i = 0; i < 6; ++i) {
        const int c = w + 8 * i;
        if (c < 32) {
            const int pan = c >> 4, sub = c & 15;
            sp[i] = aoh + (size_t)(2 * by + pan) * 524288 + sub * 512 + lane * 8;
            dof[i] = c * 1024;
        } else {
            sp[i] = woh + (size_t)bx * 524288 + (c - 32) * 512 + lane * 8;
            dof[i] = 32768 + (c - 32) * 1024;
        }
    }

    f32x4 acc[8][2] = {};

    #pragma unroll
    for (int i = 0; i < 6; ++i)
        __builtin_amdgcn_global_load_lds(
            (const __attribute__((address_space(1))) void*)(sp[i]),
            (__attribute__((address_space(3))) void*)(&lds[0][0] + dof[i]), 16, 0, 0);
    asm volatile("s_waitcnt vmcnt(0)" ::: "memory");
    __builtin_amdgcn_s_barrier();
    __builtin_amdgcn_sched_barrier(0);

    for (int t = 0; t < 64; ++t) {
        const char* b = &lds[t & 1][0];
        if (t + 1 < 64) {
            char* nb = &lds[(t + 1) & 1][0];
            #pragma unroll
            for (int i = 0; i < 6; ++i)
                __builtin_amdgcn_global_load_lds(
                    (const __attribute__((address_space(1))) void*)(sp[i] + (size_t)(t + 1) * 8192),
                    (__attribute__((address_space(3))) void*)(nb + dof[i]), 16, 0, 0);
        }
        #pragma unroll
        for (int kk = 0; kk < 2; ++kk) {
            f16x8 fb[2];
            #pragma unroll
            for (int j = 0; j < 2; ++j) {
                const int cbp = wn * 32 + j * 16 + fr;
                fb[j] = *reinterpret_cast<const f16x8*>(
                    b + 32768 + kk * 8192 + cbp * 64 + ((s4 ^ ((cbp >> 1) & 3)) << 4));
            }
            #pragma unroll
            for (int p = 0; p < 4; ++p) {
                f16x8 fh[2];
                #pragma unroll
                for (int f = 0; f < 2; ++f) {
                    const int rloc = p * 32 + f * 16 + fr;
                    fh[f] = *reinterpret_cast<const f16x8*>(
                        b + wm * 16384 + kk * 8192 + rloc * 64 + ((s4 ^ ((rloc >> 1) & 3)) << 4));
                }
                __builtin_amdgcn_s_setprio(1);
                #pragma unroll
                for (int f = 0; f < 2; ++f)
                    #pragma unroll
                    for (int j = 0; j < 2; ++j)
                        acc[p * 2 + f][j] = __builtin_amdgcn_mfma_f32_16x16x32_f16(fh[f], fb[j], acc[p * 2 + f][j], 0, 0, 0);
                __builtin_amdgcn_s_setprio(0);
            }
        }
        asm volatile("s_waitcnt vmcnt(0)" ::: "memory");
        __builtin_amdgcn_s_barrier();
        __builtin_amdgcn_sched_barrier(0);
    }

    const int r0 = by * 256 + wm * 128 + s4 * 4;
    const int c0 = bx * 128 + wn * 32 + fr;
    #pragma unroll
    for (int ri = 0; ri < 8; ++ri)
        #pragma unroll
        for (int j = 0; j < 2; ++j)
            #pragma unroll
            for (int rr = 0; rr < 4; ++rr)
                out[(size_t)(r0 + ri * 16 + rr) * 4096 + c0 + j * 16] = acc[ri][j][rr];
}

// ---------------- conv_kv: fp16 K/V in; rope on K; fp16 swizzled tiles out ----------------
__global__ __launch_bounds__(256) void conv_kv(const uint16_t* __restrict__ xk16,
                                               const uint16_t* __restrict__ xv16,
                                               uint16_t* __restrict__ kvg)
{
    __shared__ float V[32][129];
    const int t = blockIdx.x;
    const int h = blockIdx.y;
    const int tid = threadIdx.x;
    uint16_t* tile = kvg + ((size_t)(h * 64 + t)) * 8192;

    #pragma unroll
    for (int i = 0; i < 4; ++i) {
        const int v = i * 256 + tid;
        const int row = v >> 5, c4 = (v & 31) * 4;
        f16x4 hv = *reinterpret_cast<const f16x4*>(&xv16[(size_t)(t * 32 + row) * 1024 + h * 128 + c4]);
        #pragma unroll
        for (int e = 0; e < 4; ++e) V[row][c4 + e] = (float)hv[e];
    }

    {
        const int r = tid >> 3;
        const int d0 = (tid & 7) * 16;
        const int pos_ = t * 32 + r;
        float f[16];
        const uint16_t* kr = &xk16[(size_t)pos_ * 1024 + h * 128 + d0];
        f16x8 k0 = *reinterpret_cast<const f16x8*>(kr);
        f16x8 k1 = *reinterpret_cast<const f16x8*>(kr + 8);
        #pragma unroll
        for (int e = 0; e < 8; ++e) { f[e] = (float)k0[e]; f[8 + e] = (float)k1[e]; }
        #pragma unroll
        for (int i = 0; i < 8; ++i) {
            const int j = (d0 >> 1) + i;
            const float invf = exp2f(-(float)j * ROPE_C);
            const float ang = (float)pos_ * invf;
            float sn, cs;
            __sincosf(ang, &sn, &cs);
            const float x1 = f[2 * i], x2 = f[2 * i + 1];
            f[2 * i]     = x1 * cs - x2 * sn;
            f[2 * i + 1] = x1 * sn + x2 * cs;
        }
        #pragma unroll
        for (int cc = 0; cc < 2; ++cc) {
            f16x8 hv;
            #pragma unroll
            for (int e = 0; e < 8; ++e) hv[e] = (f16_t)f[cc * 8 + e];
            const int c = (d0 >> 3) + cc;
            const int pos = r * 128 + ((c ^ (r & 15)) << 3);
            *reinterpret_cast<f16x8*>(&tile[pos]) = hv;
        }
    }
    __syncthreads();
    {
        const int d = tid >> 1;
        const int k0 = (tid & 1) * 16;
        float g[16];
        #pragma unroll
        for (int j = 0; j < 16; ++j) g[j] = V[k0 + j][d];
        #pragma unroll
        for (int cc = 0; cc < 2; ++cc) {
            f16x8 hv;
            #pragma unroll
            for (int e = 0; e < 8; ++e) hv[e] = (f16_t)g[cc * 8 + e];
            const int c = (k0 >> 3) + cc;
            const int pos = 4096 + d * 32 + ((c ^ ((d >> 1) & 3)) << 3);
            *reinterpret_cast<f16x8*>(&tile[pos]) = hv;
        }
    }
}

// ---------------- MFMA flash attention: 3-buf depth-2 counted-vmcnt pipeline (r8-proven at 1 blk/CU) ----------------
__device__ __forceinline__ uint cvtpkh(float lo, float hi) {
    uint r;
    asm("v_cvt_pkrtz_f16_f32 %0, %1, %2" : "=v"(r) : "v"(lo), "v"(hi));
    return r;
}
__device__ __forceinline__ void permswap(uint& a, uint& b) {
    asm("v_permlane32_swap_b32 %0, %1" : "+v"(a), "+v"(b));
}
__device__ __forceinline__ f16x8 pack4h(uint w0, uint w1, uint w2, uint w3) {
    union { uint u[4]; f16x8 v; } t;
    t.u[0] = w0; t.u[1] = w1; t.u[2] = w2; t.u[3] = w3;
    return t.v;
}

__global__ __launch_bounds__(512, 2) void attn_mfma(const uint16_t* __restrict__ xq16,
                                                    const uint16_t* __restrict__ kvg,
                                                    uint16_t* __restrict__ aoh)
{
    __shared__ char lds[3][16384];

    const int b = blockIdx.x;
    const int kvh = b & 7;
    const int r = b >> 3;
    const int h = kvh * 4 + (r & 3);
    const int q0 = (r >> 2) * 256;
    const int tid = threadIdx.x;
    const int w = tid >> 6;
    const int lane = tid & 63;
    const int ln31 = lane & 31;
    const int hi = lane >> 5;

    const int q = q0 + w * 32 + ln31;
    const uint16_t* qrow = xq16 + (size_t)q * 4096 + h * 128;
    f16x8 Qh[8];
    #pragma unroll
    for (int ks = 0; ks < 8; ++ks) {
        const int dbase = ks * 16 + hi * 8;
        f16x8 raw = *reinterpret_cast<const f16x8*>(qrow + dbase);
        float f[8];
        #pragma unroll
        for (int e = 0; e < 8; ++e) f[e] = (float)raw[e];
        #pragma unroll
        for (int i = 0; i < 4; ++i) {
            const int j = (dbase >> 1) + i;
            const float invf = exp2f(-(float)j * ROPE_C);
            const float ang = (float)q * invf;
            float sn, cs;
            __sincosf(ang, &sn, &cs);
            const float x1 = f[2 * i], x2 = f[2 * i + 1];
            f[2 * i]     = (x1 * cs - x2 * sn) * 0.08838834764831845f;
            f[2 * i + 1] = (x1 * sn + x2 * cs) * 0.08838834764831845f;
        }
        #pragma unroll
        for (int e = 0; e < 8; ++e) Qh[ks][e] = (f16_t)f[e];
    }

    const char* gkv = (const char*)kvg + (size_t)kvh * 64 * 16384;

    f32x16 oacc[4] = {{}, {}, {}, {}};
    float m = -3.0e38f, l = 0.f;

    // prologue: stage tiles 0 and 1 (2 loads/lane each)
    #pragma unroll
    for (int tt = 0; tt < 2; ++tt) {
        const char* g = gkv + (size_t)tt * 16384;
        #pragma unroll
        for (int i = 0; i < 2; ++i) {
            const int chunk = i * 8 + w;
            __builtin_amdgcn_global_load_lds(
                (const __attribute__((address_space(1))) void*)(g + chunk * 1024 + lane * 16),
                (__attribute__((address_space(3))) void*)(&lds[tt][chunk * 1024]),
                16, 0, 0);
        }
    }

    int cur = 0;
    for (int t = 0; t < 64; ++t) {
        // tile t ready when this lane's oldest 2 loads retired; barrier makes it block-wide
        if (t + 1 < 64) asm volatile("s_waitcnt vmcnt(2)" ::: "memory");
        else            asm volatile("s_waitcnt vmcnt(0)" ::: "memory");
        __builtin_amdgcn_s_barrier();
        __builtin_amdgcn_sched_barrier(0);
        if (t + 2 < 64) {
            int nb = cur + 2; if (nb >= 3) nb -= 3;
            const char* g = gkv + (size_t)(t + 2) * 16384;
            #pragma unroll
            for (int i = 0; i < 2; ++i) {
                const int chunk = i * 8 + w;
                __builtin_amdgcn_global_load_lds(
                    (const __attribute__((address_space(1))) void*)(g + chunk * 1024 + lane * 16),
                    (__attribute__((address_space(3))) void*)(&lds[nb][chunk * 1024]),
                    16, 0, 0);
            }
        }
        const char* Kf = &lds[cur][0];
        const char* Vf = &lds[cur][0] + 8192;

        f32x16 s0 = {}, s1 = {};
        __builtin_amdgcn_s_setprio(1);
        #pragma unroll
        for (int ks = 0; ks < 8; ++ks) {
            const int byt = ln31 * 256 + ((ks * 32 + hi * 16) ^ ((ln31 & 15) << 4));
            f16x8 a = *reinterpret_cast<const f16x8*>(Kf + byt);
            if (ks & 1) s1 = __builtin_amdgcn_mfma_f32_32x32x16_f16(a, Qh[ks], s1, 0, 0, 0);
            else        s0 = __builtin_amdgcn_mfma_f32_32x32x16_f16(a, Qh[ks], s0, 0, 0, 0);
        }
        __builtin_amdgcn_s_setprio(0);
        f32x16 s = s0 + s1;

        float pmax = s[0];
        #pragma unroll
        for (int jj = 1; jj < 16; ++jj) pmax = fmaxf(pmax, s[jj]);
        pmax = fmaxf(pmax, __shfl_xor(pmax, 32));
        if (!__all(pmax - m <= 8.0f)) {
            const float mnew = fmaxf(m, pmax);
            const float corr = __expf(m - mnew);
            l *= corr;
            #pragma unroll
            for (int dt = 0; dt < 4; ++dt) oacc[dt] *= corr;
            m = mnew;
        }
        float psum = 0.f;
        #pragma unroll
        for (int jj = 0; jj < 16; ++jj) {
            float pv = __expf(s[jj] - m);
            s[jj] = pv;
            psum += pv;
        }
        psum += __shfl_xor(psum, 32);
        l += psum;

        #pragma unroll
        for (int ks = 0; ks < 2; ++ks) {
            const int b0 = ks * 8;
            uint wa = cvtpkh(s[b0 + 0], s[b0 + 1]);
            uint wb = cvtpkh(s[b0 + 2], s[b0 + 3]);
            uint wc = cvtpkh(s[b0 + 4], s[b0 + 5]);
            uint wd = cvtpkh(s[b0 + 6], s[b0 + 7]);
            permswap(wa, wc); permswap(wb, wd);
            f16x8 Pf = pack4h(wa, wb, wc, wd);
            __builtin_amdgcn_s_setprio(1);
            #pragma unroll
            for (int dt = 0; dt < 4; ++dt) {
                const int row = dt * 32 + ln31;
                const int byt = row * 64 + ((ks * 32 + hi * 16) ^ (((row >> 1) & 3) << 4));
                f16x8 vh = *reinterpret_cast<const f16x8*>(Vf + byt);
                oacc[dt] = __builtin_amdgcn_mfma_f32_32x32x16_f16(vh, Pf, oacc[dt], 0, 0, 0);
            }
            __builtin_amdgcn_s_setprio(0);
        }
        if (++cur == 3) cur = 0;
    }

    const float invl = 1.0f / l;
    const int p   = q >> 7;
    const int rr_ = q & 127;
    const int rsw = (rr_ >> 1) & 3;
    #pragma unroll
    for (int dt = 0; dt < 4; ++dt) {
        const int kb = h * 4 + dt;
        uint16_t* bh = aoh + ((size_t)p * 128 + kb) * 4096;
        #pragma unroll
        for (int g4 = 0; g4 < 4; ++g4) {
            f16x4 hv;
            #pragma unroll
            for (int e = 0; e < 4; ++e)
                hv[e] = (f16_t)(oacc[dt][g4 * 4 + e] * invl);
            const int pos = rr_ * 32 + ((g4 ^ rsw) << 3) + 4 * hi;
            *reinterpret_cast<f16x4*>(&bh[pos]) = hv;
        }
    }
}

extern "C" void kernel_launch(void* const* d_in, const int* in_sizes, int n_in,
                              void* d_out, int out_size, void* d_ws, size_t ws_size,
                              hipStream_t stream)
{
    const float* x  = (const float*)d_in[0];
    const float* wq = (const float*)d_in[1];
    const float* wk = (const float*)d_in[2];
    const float* wv = (const float*)d_in[3];
    const float* wo = (const float*)d_in[4];
    float* out = (float*)d_out;

    float* ws = (float*)d_ws;
    uint16_t* xq16 = (uint16_t*)ws;                // fp16 Q [2048][4096]
    uint16_t* kvg  = (uint16_t*)(ws + 8388608);    // fp16 K/V tiles (8.4 MB)
    uint16_t* xk16 = (uint16_t*)(ws + 12582912);
    uint16_t* xv16 = (uint16_t*)(ws + 14680064);
    uint16_t* aoh  = (uint16_t*)(ws + 12582912);   // reuses xk slot after conv_kv
    uint16_t* xh   = (uint16_t*)(ws + 20971520);   // fp16 packed x
    uint16_t* wqkv = (uint16_t*)(ws + 29360128);   // fp16 packed wq|wk|wv
    uint16_t* woh  = (uint16_t*)(ws + 41943040);   // fp16 packed wo

    dim3 blk(256);
    repack_all<<<dim3(14336), blk, 0, stream>>>(x, wq, wk, wv, wo, xh, wqkv, woh);
    gemm_qkv9 <<<dim3(512), dim3(512), 0, stream>>>(xh, wqkv, xq16, xk16, xv16);
    conv_kv   <<<dim3(64, 8), blk, 0, stream>>>(xk16, xv16, kvg);
    attn_mfma <<<dim3(256), dim3(512), 0, stream>>>(xq16, kvg, aoh);
    gemm_out8 <<<dim3(256), dim3(512), 0, stream>>>(aoh, woh, out);
}

// Round 21
// 340.039 us; speedup vs baseline: 1.0068x; 1.0068x over previous
//
#include <hip/hip_runtime.h>
#include <hip/hip_bf16.h>

typedef _Float16 f16_t;
typedef unsigned int uint;
typedef __attribute__((ext_vector_type(8))) _Float16 f16x8;
typedef __attribute__((ext_vector_type(4))) _Float16 f16x4;
typedef __attribute__((ext_vector_type(4))) float f32x4;
typedef __attribute__((ext_vector_type(16))) float f32x16;

#define ROPE_C (13.287712379549449f / 64.0f)   // log2(10000)/64; invf(j)=exp2(-j*ROPE_C)

// ---------------- merged repack: x (blocks 0..2047), wq|wk|wv 96-pan (2048..10239), wo (10240..14335) ----------------
__global__ __launch_bounds__(256) void repack_all(const float* __restrict__ x,
                                                  const float* __restrict__ wq,
                                                  const float* __restrict__ wk,
                                                  const float* __restrict__ wv,
                                                  const float* __restrict__ wo,
                                                  uint16_t* __restrict__ xh,
                                                  uint16_t* __restrict__ wqkv,
                                                  uint16_t* __restrict__ woh)
{
    const int bid = blockIdx.x;
    const int tid = threadIdx.x;
    const int k4 = tid & 7;
    const int slot = k4 >> 1;
    const int so   = (k4 & 1) * 4;

    if (bid < 2048) {
        const int p  = bid >> 7;
        const int kb = bid & 127;
        const int rr = tid >> 3;
        uint16_t* bh = xh + ((size_t)p * 128 + kb) * 4096;
        #pragma unroll
        for (int it = 0; it < 4; ++it) {
            const int r = it * 32 + rr;
            const float4 v = *reinterpret_cast<const float4*>(
                &x[((size_t)p * 128 + r) * 4096 + kb * 32 + k4 * 4]);
            float f[4] = {v.x, v.y, v.z, v.w};
            f16x4 h;
            #pragma unroll
            for (int e = 0; e < 4; ++e) h[e] = (f16_t)f[e];
            const int pos = r * 32 + ((slot ^ ((r >> 1) & 3)) << 3) + so;
            *reinterpret_cast<f16x4*>(&bh[pos]) = h;
        }
    } else if (bid < 10240) {
        const int idx = bid - 2048;
        const int pan = idx >> 7;
        const int kb  = idx & 127;
        uint16_t* bh = wqkv + ((size_t)pan * 128 + kb) * 3072;
        #pragma unroll
        for (int it = 0; it < 3; ++it) {
            const int r = it * 32 + (tid >> 3);
            const int n = pan * 96 + r;
            const float* srow = (n < 4096) ? (wq + (size_t)n * 4096)
                              : (n < 5120) ? (wk + (size_t)(n - 4096) * 4096)
                                           : (wv + (size_t)(n - 5120) * 4096);
            const float4 v = *reinterpret_cast<const float4*>(srow + kb * 32 + k4 * 4);
            float f[4] = {v.x, v.y, v.z, v.w};
            f16x4 h;
            #pragma unroll
            for (int e = 0; e < 4; ++e) h[e] = (f16_t)f[e];
            const int pos = r * 32 + ((slot ^ ((r >> 1) & 3)) << 3) + so;
            *reinterpret_cast<f16x4*>(&bh[pos]) = h;
        }
    } else {
        const int idx = bid - 10240;
        const int p  = idx >> 7;
        const int kb = idx & 127;
        const int rr = tid >> 3;
        uint16_t* bh = woh + ((size_t)p * 128 + kb) * 4096;
        #pragma unroll
        for (int it = 0; it < 4; ++it) {
            const int r = it * 32 + rr;
            const float4 v = *reinterpret_cast<const float4*>(
                &wo[((size_t)p * 128 + r) * 4096 + kb * 32 + k4 * 4]);
            float f[4] = {v.x, v.y, v.z, v.w};
            f16x4 h;
            #pragma unroll
            for (int e = 0; e < 4; ++e) h[e] = (f16_t)f[e];
            const int pos = r * 32 + ((slot ^ ((r >> 1) & 3)) << 3) + so;
            *reinterpret_cast<f16x4*>(&bh[pos]) = h;
        }
    }
}

// ---------------- QKV GEMM: 128x192, fp16, BK=64, 2-buf, grid 512; 2-D XCD partition ----------------
__global__ __launch_bounds__(512) void gemm_qkv9(const uint16_t* __restrict__ xh,
                                                 const uint16_t* __restrict__ wqkv,
                                                 uint16_t* __restrict__ xq16,
                                                 uint16_t* __restrict__ xk16,
                                                 uint16_t* __restrict__ xv16)
{
    __shared__ char lds[2][40960];

    const int bid = blockIdx.x;
    const int xcd = bid & 7;
    const int i_  = bid >> 3;
    const int by = (xcd & 1) * 8 + (i_ & 7);
    const int bx = (xcd >> 1) * 8 + (i_ >> 3);
    const int tid = threadIdx.x;
    const int w = tid >> 6, lane = tid & 63;
    const int wm = w >> 2, wn = w & 3;
    const int fr = lane & 15, s4 = lane >> 4;

    const uint16_t* sp[5];
    int dof[5];
    int stridec[5];
    #pragma unroll
    for (int i = 0; i < 5; ++i) {
        const int c = w + 8 * i;
        if (c < 16) {
            const int kk = c >> 3, inner = c & 7;
            sp[i] = xh + (size_t)by * 524288 + kk * 4096 + inner * 512 + lane * 8;
            dof[i] = c * 1024;
            stridec[i] = 8192;
        } else {
            const int cb = c - 16;
            const int pan = cb / 12, rem = cb % 12;
            const int kk = rem / 6, inner = rem % 6;
            sp[i] = wqkv + (size_t)(bx * 2 + pan) * 393216 + kk * 3072 + inner * 512 + lane * 8;
            dof[i] = 16384 + cb * 1024;
            stridec[i] = 6144;
        }
    }

    f32x4 acc[4][3] = {};

    #pragma unroll
    for (int i = 0; i < 5; ++i)
        __builtin_amdgcn_global_load_lds(
            (const __attribute__((address_space(1))) void*)(sp[i]),
            (__attribute__((address_space(3))) void*)(&lds[0][0] + dof[i]), 16, 0, 0);
    asm volatile("s_waitcnt vmcnt(0)" ::: "memory");
    __builtin_amdgcn_s_barrier();
    __builtin_amdgcn_sched_barrier(0);

    for (int t = 0; t < 64; ++t) {
        const char* b = &lds[t & 1][0];
        if (t + 1 < 64) {
            char* nb = &lds[(t + 1) & 1][0];
            #pragma unroll
            for (int i = 0; i < 5; ++i)
                __builtin_amdgcn_global_load_lds(
                    (const __attribute__((address_space(1))) void*)(sp[i] + (size_t)(t + 1) * stridec[i]),
                    (__attribute__((address_space(3))) void*)(nb + dof[i]), 16, 0, 0);
        }
        #pragma unroll
        for (int kk = 0; kk < 2; ++kk) {
            f16x8 fb[3];
            #pragma unroll
            for (int j = 0; j < 3; ++j) {
                const int cbp = wn * 48 + j * 16 + fr;
                const int pan = (cbp >= 96) ? 1 : 0;
                const int rb = cbp - pan * 96;
                fb[j] = *reinterpret_cast<const f16x8*>(
                    b + 16384 + pan * 12288 + kk * 6144 + rb * 64 + ((s4 ^ ((rb >> 1) & 3)) << 4));
            }
            #pragma unroll
            for (int ri = 0; ri < 4; ++ri) {
                const int rloc = wm * 64 + ri * 16 + fr;
                f16x8 fh = *reinterpret_cast<const f16x8*>(
                    b + kk * 8192 + rloc * 64 + ((s4 ^ ((rloc >> 1) & 3)) << 4));
                __builtin_amdgcn_s_setprio(1);
                #pragma unroll
                for (int j = 0; j < 3; ++j)
                    acc[ri][j] = __builtin_amdgcn_mfma_f32_16x16x32_f16(fh, fb[j], acc[ri][j], 0, 0, 0);
                __builtin_amdgcn_s_setprio(0);
            }
        }
        asm volatile("s_waitcnt vmcnt(0)" ::: "memory");
        __builtin_amdgcn_s_barrier();
        __builtin_amdgcn_sched_barrier(0);
    }

    const int r0 = by * 128 + wm * 64 + s4 * 4;
    const int c0 = bx * 192 + wn * 48 + fr;
    #pragma unroll
    for (int ri = 0; ri < 4; ++ri)
        #pragma unroll
        for (int j = 0; j < 3; ++j) {
            const int col = c0 + j * 16;
            #pragma unroll
            for (int rr = 0; rr < 4; ++rr) {
                const int row = r0 + ri * 16 + rr;
                const f16_t v = (f16_t)acc[ri][j][rr];
                uint16_t bits;
                __builtin_memcpy(&bits, &v, 2);
                if (col < 4096)      xq16[(size_t)row * 4096 + col] = bits;
                else if (col < 5120) xk16[(size_t)row * 1024 + (col - 4096)] = bits;
                else                 xv16[(size_t)row * 1024 + (col - 5120)] = bits;
            }
        }
}

// ---------------- Output GEMM: 256x128, fp16, BK=64, 2-buf, grid 256; 2-D XCD partition ----------------
__global__ __launch_bounds__(512) void gemm_out8(const uint16_t* __restrict__ aoh,
                                                 const uint16_t* __restrict__ woh,
                                                 float* __restrict__ out)
{
    __shared__ char lds[2][49152];

    const int bid = blockIdx.x;
    const int xcd = bid & 7;
    const int i_  = bid >> 3;
    const int by = (xcd & 1) * 4 + (i_ & 3);
    const int bx = (xcd >> 1) * 8 + (i_ >> 2);
    const int tid = threadIdx.x;
    const int w = tid >> 6, lane = tid & 63;
    const int wm = w >> 2, wn = w & 3;
    const int fr = lane & 15, s4 = lane >> 4;

    const uint16_t* sp[6];
    int dof[6];
    #pragma unroll
    for (int i = 0; i < 6; ++i) {
        const int c = w + 8 * i;
        if (c < 32) {
            const int pan = c >> 4, sub = c & 15;
            sp[i] = aoh + (size_t)(2 * by + pan) * 524288 + sub * 512 + lane * 8;
            dof[i] = c * 1024;
        } else {
            sp[i] = woh + (size_t)bx * 524288 + (c - 32) * 512 + lane * 8;
            dof[i] = 32768 + (c - 32) * 1024;
        }
    }

    f32x4 acc[8][2] = {};

    #pragma unroll
    for (int i = 0; i < 6; ++i)
        __builtin_amdgcn_global_load_lds(
            (const __attribute__((address_space(1))) void*)(sp[i]),
            (__attribute__((address_space(3))) void*)(&lds[0][0] + dof[i]), 16, 0, 0);
    asm volatile("s_waitcnt vmcnt(0)" ::: "memory");
    __builtin_amdgcn_s_barrier();
    __builtin_amdgcn_sched_barrier(0);

    for (int t = 0; t < 64; ++t) {
        const char* b = &lds[t & 1][0];
        if (t + 1 < 64) {
            char* nb = &lds[(t + 1) & 1][0];
            #pragma unroll
            for (int i = 0; i < 6; ++i)
                __builtin_amdgcn_global_load_lds(
                    (const __attribute__((address_space(1))) void*)(sp[i] + (size_t)(t + 1) * 8192),
                    (__attribute__((address_space(3))) void*)(nb + dof[i]), 16, 0, 0);
        }
        #pragma unroll
        for (int kk = 0; kk < 2; ++kk) {
            f16x8 fb[2];
            #pragma unroll
            for (int j = 0; j < 2; ++j) {
                const int cbp = wn * 32 + j * 16 + fr;
                fb[j] = *reinterpret_cast<const f16x8*>(
                    b + 32768 + kk * 8192 + cbp * 64 + ((s4 ^ ((cbp >> 1) & 3)) << 4));
            }
            #pragma unroll
            for (int p = 0; p < 4; ++p) {
                f16x8 fh[2];
                #pragma unroll
                for (int f = 0; f < 2; ++f) {
                    const int rloc = p * 32 + f * 16 + fr;
                    fh[f] = *reinterpret_cast<const f16x8*>(
                        b + wm * 16384 + kk * 8192 + rloc * 64 + ((s4 ^ ((rloc >> 1) & 3)) << 4));
                }
                __builtin_amdgcn_s_setprio(1);
                #pragma unroll
                for (int f = 0; f < 2; ++f)
                    #pragma unroll
                    for (int j = 0; j < 2; ++j)
                        acc[p * 2 + f][j] = __builtin_amdgcn_mfma_f32_16x16x32_f16(fh[f], fb[j], acc[p * 2 + f][j], 0, 0, 0);
                __builtin_amdgcn_s_setprio(0);
            }
        }
        asm volatile("s_waitcnt vmcnt(0)" ::: "memory");
        __builtin_amdgcn_s_barrier();
        __builtin_amdgcn_sched_barrier(0);
    }

    const int r0 = by * 256 + wm * 128 + s4 * 4;
    const int c0 = bx * 128 + wn * 32 + fr;
    #pragma unroll
    for (int ri = 0; ri < 8; ++ri)
        #pragma unroll
        for (int j = 0; j < 2; ++j)
            #pragma unroll
            for (int rr = 0; rr < 4; ++rr)
                out[(size_t)(r0 + ri * 16 + rr) * 4096 + c0 + j * 16] = acc[ri][j][rr];
}

// ---------------- conv_kv: fp16 K/V in; rope on K; fp16 swizzled tiles out ----------------
__global__ __launch_bounds__(256) void conv_kv(const uint16_t* __restrict__ xk16,
                                               const uint16_t* __restrict__ xv16,
                                               uint16_t* __restrict__ kvg)
{
    __shared__ float V[32][129];
    const int t = blockIdx.x;
    const int h = blockIdx.y;
    const int tid = threadIdx.x;
    uint16_t* tile = kvg + ((size_t)(h * 64 + t)) * 8192;

    #pragma unroll
    for (int i = 0; i < 4; ++i) {
        const int v = i * 256 + tid;
        const int row = v >> 5, c4 = (v & 31) * 4;
        f16x4 hv = *reinterpret_cast<const f16x4*>(&xv16[(size_t)(t * 32 + row) * 1024 + h * 128 + c4]);
        #pragma unroll
        for (int e = 0; e < 4; ++e) V[row][c4 + e] = (float)hv[e];
    }

    {
        const int r = tid >> 3;
        const int d0 = (tid & 7) * 16;
        const int pos_ = t * 32 + r;
        float f[16];
        const uint16_t* kr = &xk16[(size_t)pos_ * 1024 + h * 128 + d0];
        f16x8 k0 = *reinterpret_cast<const f16x8*>(kr);
        f16x8 k1 = *reinterpret_cast<const f16x8*>(kr + 8);
        #pragma unroll
        for (int e = 0; e < 8; ++e) { f[e] = (float)k0[e]; f[8 + e] = (float)k1[e]; }
        #pragma unroll
        for (int i = 0; i < 8; ++i) {
            const int j = (d0 >> 1) + i;
            const float invf = exp2f(-(float)j * ROPE_C);
            const float ang = (float)pos_ * invf;
            float sn, cs;
            __sincosf(ang, &sn, &cs);
            const float x1 = f[2 * i], x2 = f[2 * i + 1];
            f[2 * i]     = x1 * cs - x2 * sn;
            f[2 * i + 1] = x1 * sn + x2 * cs;
        }
        #pragma unroll
        for (int cc = 0; cc < 2; ++cc) {
            f16x8 hv;
            #pragma unroll
            for (int e = 0; e < 8; ++e) hv[e] = (f16_t)f[cc * 8 + e];
            const int c = (d0 >> 3) + cc;
            const int pos = r * 128 + ((c ^ (r & 15)) << 3);
            *reinterpret_cast<f16x8*>(&tile[pos]) = hv;
        }
    }
    __syncthreads();
    {
        const int d = tid >> 1;
        const int k0 = (tid & 1) * 16;
        float g[16];
        #pragma unroll
        for (int j = 0; j < 16; ++j) g[j] = V[k0 + j][d];
        #pragma unroll
        for (int cc = 0; cc < 2; ++cc) {
            f16x8 hv;
            #pragma unroll
            for (int e = 0; e < 8; ++e) hv[e] = (f16_t)g[cc * 8 + e];
            const int c = (k0 >> 3) + cc;
            const int pos = 4096 + d * 32 + ((c ^ ((d >> 1) & 3)) << 3);
            *reinterpret_cast<f16x8*>(&tile[pos]) = hv;
        }
    }
}

// ---------------- MFMA flash attention: T15 double-pipeline (QK(t) overlaps softmax+PV(t-1)) ----------------
__device__ __forceinline__ uint cvtpkh(float lo, float hi) {
    uint r;
    asm("v_cvt_pkrtz_f16_f32 %0, %1, %2" : "=v"(r) : "v"(lo), "v"(hi));
    return r;
}
__device__ __forceinline__ void permswap(uint& a, uint& b) {
    asm("v_permlane32_swap_b32 %0, %1" : "+v"(a), "+v"(b));
}
__device__ __forceinline__ f16x8 pack4h(uint w0, uint w1, uint w2, uint w3) {
    union { uint u[4]; f16x8 v; } t;
    t.u[0] = w0; t.u[1] = w1; t.u[2] = w2; t.u[3] = w3;
    return t.v;
}

__global__ __launch_bounds__(512, 1) void attn_mfma(const uint16_t* __restrict__ xq16,
                                                    const uint16_t* __restrict__ kvg,
                                                    uint16_t* __restrict__ aoh)
{
    __shared__ char lds[4][16384];

    const int b = blockIdx.x;
    const int kvh = b & 7;
    const int r = b >> 3;
    const int h = kvh * 4 + (r & 3);
    const int q0 = (r >> 2) * 256;
    const int tid = threadIdx.x;
    const int w = tid >> 6;
    const int lane = tid & 63;
    const int ln31 = lane & 31;
    const int hi = lane >> 5;

    const int q = q0 + w * 32 + ln31;
    const uint16_t* qrow = xq16 + (size_t)q * 4096 + h * 128;
    f16x8 Qh[8];
    #pragma unroll
    for (int ks = 0; ks < 8; ++ks) {
        const int dbase = ks * 16 + hi * 8;
        f16x8 raw = *reinterpret_cast<const f16x8*>(qrow + dbase);
        float f[8];
        #pragma unroll
        for (int e = 0; e < 8; ++e) f[e] = (float)raw[e];
        #pragma unroll
        for (int i = 0; i < 4; ++i) {
            const int j = (dbase >> 1) + i;
            const float invf = exp2f(-(float)j * ROPE_C);
            const float ang = (float)q * invf;
            float sn, cs;
            __sincosf(ang, &sn, &cs);
            const float x1 = f[2 * i], x2 = f[2 * i + 1];
            f[2 * i]     = (x1 * cs - x2 * sn) * 0.08838834764831845f;
            f[2 * i + 1] = (x1 * sn + x2 * cs) * 0.08838834764831845f;
        }
        #pragma unroll
        for (int e = 0; e < 8; ++e) Qh[ks][e] = (f16_t)f[e];
    }

    const char* gkv = (const char*)kvg + (size_t)kvh * 64 * 16384;

    f32x16 oacc[4] = {{}, {}, {}, {}};
    float m = -3.0e38f, l = 0.f;
    f32x16 s0A, s1A, s0B, s1B;

    // wait for tile T_, barrier, then issue staging of T_+2 into buf (T_+2)&3
#define WAIT_STAGE(T_) do {                                                         \
        if ((T_) + 1 < 64) asm volatile("s_waitcnt vmcnt(2)" ::: "memory");          \
        else               asm volatile("s_waitcnt vmcnt(0)" ::: "memory");          \
        __builtin_amdgcn_s_barrier();                                                \
        __builtin_amdgcn_sched_barrier(0);                                           \
        if ((T_) + 2 < 64) {                                                         \
            const char* g_ = gkv + (size_t)((T_) + 2) * 16384;                       \
            char* dst_ = &lds[((T_) + 2) & 3][0];                                    \
            _Pragma("unroll")                                                        \
            for (int i_ = 0; i_ < 2; ++i_) {                                         \
                const int chunk_ = i_ * 8 + w;                                       \
                __builtin_amdgcn_global_load_lds(                                    \
                    (const __attribute__((address_space(1))) void*)(g_ + chunk_ * 1024 + lane * 16), \
                    (__attribute__((address_space(3))) void*)(dst_ + chunk_ * 1024), \
                    16, 0, 0);                                                       \
            }                                                                        \
        }                                                                            \
    } while (0)

#define QK_TILE(T_, S0_, S1_) do {                                                  \
        const char* Kf_ = &lds[(T_) & 3][0];                                        \
        S0_ = (f32x16){};                                                           \
        S1_ = (f32x16){};                                                           \
        __builtin_amdgcn_s_setprio(1);                                              \
        _Pragma("unroll")                                                           \
        for (int ks_ = 0; ks_ < 8; ++ks_) {                                         \
            const int byt_ = ln31 * 256 + ((ks_ * 32 + hi * 16) ^ ((ln31 & 15) << 4)); \
            f16x8 a_ = *reinterpret_cast<const f16x8*>(Kf_ + byt_);                 \
            if (ks_ & 1) S1_ = __builtin_amdgcn_mfma_f32_32x32x16_f16(a_, Qh[ks_], S1_, 0, 0, 0); \
            else         S0_ = __builtin_amdgcn_mfma_f32_32x32x16_f16(a_, Qh[ks_], S0_, 0, 0, 0); \
        }                                                                           \
        __builtin_amdgcn_s_setprio(0);                                              \
    } while (0)

#define SMPV_TILE(T_, S0_, S1_) do {                                                \
        const char* Vf_ = &lds[(T_) & 3][0] + 8192;                                 \
        f32x16 s_ = S0_ + S1_;                                                      \
        float pmax_ = s_[0];                                                        \
        _Pragma("unroll")                                                           \
        for (int jj_ = 1; jj_ < 16; ++jj_) pmax_ = fmaxf(pmax_, s_[jj_]);           \
        pmax_ = fmaxf(pmax_, __shfl_xor(pmax_, 32));                                \
        if (!__all(pmax_ - m <= 8.0f)) {                                            \
            const float mnew_ = fmaxf(m, pmax_);                                    \
            const float corr_ = __expf(m - mnew_);                                  \
            l *= corr_;                                                             \
            _Pragma("unroll")                                                       \
            for (int dt_ = 0; dt_ < 4; ++dt_) oacc[dt_] *= corr_;                   \
            m = mnew_;                                                              \
        }                                                                           \
        float psum_ = 0.f;                                                          \
        _Pragma("unroll")                                                           \
        for (int jj_ = 0; jj_ < 16; ++jj_) {                                        \
            float pv_ = __expf(s_[jj_] - m);                                        \
            s_[jj_] = pv_;                                                          \
            psum_ += pv_;                                                           \
        }                                                                           \
        psum_ += __shfl_xor(psum_, 32);                                             \
        l += psum_;                                                                 \
        _Pragma("unroll")                                                           \
        for (int ks_ = 0; ks_ < 2; ++ks_) {                                         \
            const int b0_ = ks_ * 8;                                                \
            uint wa_ = cvtpkh(s_[b0_ + 0], s_[b0_ + 1]);                            \
            uint wb_ = cvtpkh(s_[b0_ + 2], s_[b0_ + 3]);                            \
            uint wc_ = cvtpkh(s_[b0_ + 4], s_[b0_ + 5]);                            \
            uint wd_ = cvtpkh(s_[b0_ + 6], s_[b0_ + 7]);                            \
            permswap(wa_, wc_); permswap(wb_, wd_);                                 \
            f16x8 Pf_ = pack4h(wa_, wb_, wc_, wd_);                                 \
            __builtin_amdgcn_s_setprio(1);                                          \
            _Pragma("unroll")                                                       \
            for (int dt_ = 0; dt_ < 4; ++dt_) {                                     \
                const int row_ = dt_ * 32 + ln31;                                   \
                const int byt_ = row_ * 64 + ((ks_ * 32 + hi * 16) ^ (((row_ >> 1) & 3) << 4)); \
                f16x8 vh_ = *reinterpret_cast<const f16x8*>(Vf_ + byt_);            \
                oacc[dt_] = __builtin_amdgcn_mfma_f32_32x32x16_f16(vh_, Pf_, oacc[dt_], 0, 0, 0); \
            }                                                                       \
            __builtin_amdgcn_s_setprio(0);                                          \
        }                                                                           \
    } while (0)

    // prologue: stage tiles 0 and 1
    #pragma unroll
    for (int tt = 0; tt < 2; ++tt) {
        const char* g = gkv + (size_t)tt * 16384;
        #pragma unroll
        for (int i = 0; i < 2; ++i) {
            const int chunk = i * 8 + w;
            __builtin_amdgcn_global_load_lds(
                (const __attribute__((address_space(1))) void*)(g + chunk * 1024 + lane * 16),
                (__attribute__((address_space(3))) void*)(&lds[tt][chunk * 1024]),
                16, 0, 0);
        }
    }

    // t = 0: QK only
    WAIT_STAGE(0);
    QK_TILE(0, s0A, s1A);

    // pipelined pairs: QK(t) overlaps softmax+PV(t-1)
    for (int tp = 1; tp < 64; tp += 2) {
        WAIT_STAGE(tp);
        QK_TILE(tp, s0B, s1B);
        SMPV_TILE(tp - 1, s0A, s1A);
        if (tp + 1 < 64) {
            WAIT_STAGE(tp + 1);
            QK_TILE(tp + 1, s0A, s1A);
            SMPV_TILE(tp, s0B, s1B);
        }
    }
    // tail: tile 63 (odd -> B state)
    SMPV_TILE(63, s0B, s1B);

#undef WAIT_STAGE
#undef QK_TILE
#undef SMPV_TILE

    const float invl = 1.0f / l;
    const int p   = q >> 7;
    const int rr_ = q & 127;
    const int rsw = (rr_ >> 1) & 3;
    #pragma unroll
    for (int dt = 0; dt < 4; ++dt) {
        const int kb = h * 4 + dt;
        uint16_t* bh = aoh + ((size_t)p * 128 + kb) * 4096;
        #pragma unroll
        for (int g4 = 0; g4 < 4; ++g4) {
            f16x4 hv;
            #pragma unroll
            for (int e = 0; e < 4; ++e)
                hv[e] = (f16_t)(oacc[dt][g4 * 4 + e] * invl);
            const int pos = rr_ * 32 + ((g4 ^ rsw) << 3) + 4 * hi;
            *reinterpret_cast<f16x4*>(&bh[pos]) = hv;
        }
    }
}

extern "C" void kernel_launch(void* const* d_in, const int* in_sizes, int n_in,
                              void* d_out, int out_size, void* d_ws, size_t ws_size,
                              hipStream_t stream)
{
    const float* x  = (const float*)d_in[0];
    const float* wq = (const float*)d_in[1];
    const float* wk = (const float*)d_in[2];
    const float* wv = (const float*)d_in[3];
    const float* wo = (const float*)d_in[4];
    float* out = (float*)d_out;

    float* ws = (float*)d_ws;
    uint16_t* xq16 = (uint16_t*)ws;                // fp16 Q [2048][4096]
    uint16_t* kvg  = (uint16_t*)(ws + 8388608);    // fp16 K/V tiles (8.4 MB)
    uint16_t* xk16 = (uint16_t*)(ws + 12582912);
    uint16_t* xv16 = (uint16_t*)(ws + 14680064);
    uint16_t* aoh  = (uint16_t*)(ws + 12582912);   // reuses xk slot after conv_kv
    uint16_t* xh   = (uint16_t*)(ws + 20971520);   // fp16 packed x
    uint16_t* wqkv = (uint16_t*)(ws + 29360128);   // fp16 packed wq|wk|wv
    uint16_t* woh  = (uint16_t*)(ws + 41943040);   // fp16 packed wo

    dim3 blk(256);
    repack_all<<<dim3(14336), blk, 0, stream>>>(x, wq, wk, wv, wo, xh, wqkv, woh);
    gemm_qkv9 <<<dim3(512), dim3(512), 0, stream>>>(xh, wqkv, xq16, xk16, xv16);
    conv_kv   <<<dim3(64, 8), blk, 0, stream>>>(xk16, xv16, kvg);
    attn_mfma <<<dim3(256), dim3(512), 0, stream>>>(xq16, kvg, aoh);
    gemm_out8 <<<dim3(256), dim3(512), 0, stream>>>(aoh, woh, out);
}